// Round 17
// baseline (44.288 us; speedup 1.0000x reference)
//
#include <hip/hip_runtime.h>
#include <math.h>

#define NP 512
#define NS 512
#define DD 512
#define INV64 0.015625f
#define NEGBIG -1000000000.0f
#define LOG2E 1.4426950408889634f

// ws float offsets
#define WS_MTBF   0         // 512*512 bf16
#define WS_TBF    131072    // 4096*512 bf16
#define WS_PBF    1179648   // 4096*512 bf16
#define WS_SBF    2228224   // 4096*512 bf16
#define WS_WV     3538944   // 512
#define WS_U      3539456   // 512
#define WS_WQBK   3539968   // 512
#define WS_WKBQ   3540480   // 512
#define WS_VV     3540992   // 4096
#define WS_A      3545088   // 4096
#define WS_E      3549184   // 4096
#define WS_CP     3553280   // 4096
#define WS_CS     3557376   // 4096
#define WS_Z      3561472   // 4096
#define WS_W      3565568   // 4096 (must be WS_Z+4096: zeroed together)
#define WS_SC     3569664   // [0]=bv.wv [1]=bo.Wval+bval [2]=bq.bk
#define WS_CNT    3569680   // 64 unsigned ticket counters (zeroed by kU)

#define OUT_SCORES 0
#define OUT_VALUE  2097152
#define OUT_COMP   2097160

typedef short bf16x8 __attribute__((ext_vector_type(8)));
typedef float f32x4 __attribute__((ext_vector_type(4)));

__device__ __forceinline__ short f2bf(float f) {
  unsigned u = __builtin_bit_cast(unsigned, f);
  u += 0x7fffu + ((u >> 16) & 1u);
  return (short)(u >> 16);
}

__device__ __forceinline__ float bf2f(short s) {
  unsigned u = ((unsigned)(unsigned short)s) << 16;
  return __builtin_bit_cast(float, u);
}

__device__ __forceinline__ bf16x8 cvt8(float4 a, float4 b) {
  bf16x8 o;
  o[0] = f2bf(a.x); o[1] = f2bf(a.y); o[2] = f2bf(a.z); o[3] = f2bf(a.w);
  o[4] = f2bf(b.x); o[5] = f2bf(b.y); o[6] = f2bf(b.z); o[7] = f2bf(b.w);
  return o;
}

__device__ __forceinline__ void async_copy16(const void* g, void* l) {
  __builtin_amdgcn_global_load_lds(
      (const __attribute__((address_space(1))) unsigned int*)g,
      (__attribute__((address_space(3))) unsigned int*)l, 16, 0, 0);
}

__device__ __forceinline__ float dot8(float4 a0, float4 a1, float4 b0, float4 b1) {
  return a0.x * b0.x + a0.y * b0.y + a0.z * b0.z + a0.w * b0.w +
         a1.x * b1.x + a1.y * b1.y + a1.z * b1.z + a1.w * b1.w;
}

__device__ __forceinline__ float wave_red(float s) {
#pragma unroll
  for (int o = 32; o; o >>= 1) s += __shfl_xor(s, o);
  return s;
}

__device__ inline float wave_dot512(const float* __restrict__ x,
                                    const float* __restrict__ y, int lane) {
  float4 x0 = *(const float4*)&x[lane * 8];
  float4 x1 = *(const float4*)&x[lane * 8 + 4];
  float4 y0 = *(const float4*)&y[lane * 8];
  float4 y1 = *(const float4*)&y[lane * 8 + 4];
  return wave_red(dot8(x0, x1, y0, y1));
}

// ---- L1 kAM: row-dots (0..384) + MT GEMM (385..448) + piece cvt/cp (449..1472)
__global__ __launch_bounds__(256) void kAM(
    const float* __restrict__ Wo, const float* __restrict__ Wval,
    const float* __restrict__ Wq, const float* __restrict__ bk,
    const float* __restrict__ Wk, const float* __restrict__ bq,
    const float* __restrict__ bo, const float* __restrict__ bval,
    const float* __restrict__ piece, const float* __restrict__ Wc,
    float* __restrict__ ws, short* __restrict__ mtb, short* __restrict__ pbf) {
  __shared__ alignas(16) short Asw[2][64 * 72];
  __shared__ alignas(16) short Bsw[2][64 * 72];
  int blk = blockIdx.x;
  const int wave = threadIdx.x >> 6, lane = threadIdx.x & 63;
  if (blk < 385) {
    int wid = blk * 4 + wave;
    if (wid >= 1538) return;
    const float *x, *y;
    float* dst;
    float extra = 0.f;
    int r = wid & 511;
    if (wid < 512)        { x = Wo + (size_t)r * DD; y = Wval; dst = ws + WS_WV + r; }
    else if (wid < 1024)  { x = Wq + (size_t)r * DD; y = bk;   dst = ws + WS_WQBK + r; }
    else if (wid < 1536)  { x = Wk + (size_t)r * DD; y = bq;   dst = ws + WS_WKBQ + r; }
    else if (wid == 1536) { x = bo; y = Wval; dst = ws + WS_SC + 1; extra = *bval; }
    else                  { x = bq; y = bk;   dst = ws + WS_SC + 2; }
    float s = wave_dot512(x, y, lane);
    if (lane == 0) *dst = s + extra;
    return;
  }
  if (blk >= 449) {  // piece: bf16 cvt + cp-dot (inputs only; a-dot moved to L2)
    int wid = (blk - 449) * 4 + wave;  // 0..4095
    const float* row = piece + (size_t)wid * DD;
    float4 x0 = *(const float4*)&row[lane * 8];
    float4 x1 = *(const float4*)&row[lane * 8 + 4];
    *(bf16x8*)&pbf[(size_t)wid * DD + lane * 8] = cvt8(x0, x1);
    float4 c0 = *(const float4*)&Wc[lane * 8];
    float4 c1 = *(const float4*)&Wc[lane * 8 + 4];
    float dc = wave_red(dot8(x0, x1, c0, c1));
    if (lane == 0) ws[WS_CP + wid] = dc;
    return;
  }
  // MT GEMM: 64 blocks, 64x64 tile, f32 inputs with on-the-fly bf16 cvt
  int gb = blk - 385;
  const int m0 = (gb & 7) * 64, n0 = (gb >> 3) * 64;
  const int wr = wave >> 1, wc = wave & 1;
  const int li = lane & 15, g = lane >> 4;
  const int arow = threadIdx.x >> 2, aseg = threadIdx.x & 3;
  f32x4 acc[2][2] = {};

  auto stage = [&](int bufi, int k0) {
    const float* sa = Wk + (size_t)(m0 + arow) * DD + k0 + aseg * 16;
    float4 a0 = *(const float4*)sa, a1 = *(const float4*)(sa + 4);
    float4 a2 = *(const float4*)(sa + 8), a3 = *(const float4*)(sa + 12);
    const float* sb = Wq + (size_t)(n0 + arow) * DD + k0 + aseg * 16;
    float4 b0 = *(const float4*)sb, b1 = *(const float4*)(sb + 4);
    float4 b2 = *(const float4*)(sb + 8), b3 = *(const float4*)(sb + 12);
    *(bf16x8*)&Asw[bufi][arow * 72 + aseg * 16] = cvt8(a0, a1);
    *(bf16x8*)&Asw[bufi][arow * 72 + aseg * 16 + 8] = cvt8(a2, a3);
    *(bf16x8*)&Bsw[bufi][arow * 72 + aseg * 16] = cvt8(b0, b1);
    *(bf16x8*)&Bsw[bufi][arow * 72 + aseg * 16 + 8] = cvt8(b2, b3);
  };

  stage(0, 0);
  __syncthreads();
  int buf = 0;
  for (int k0 = 0; k0 < DD; k0 += 64) {
    if (k0 + 64 < DD) stage(buf ^ 1, k0 + 64);
    bf16x8 af[2][2], bfv[2][2];
#pragma unroll
    for (int kk = 0; kk < 2; ++kk) {
#pragma unroll
      for (int am = 0; am < 2; ++am)
        af[am][kk] = *(const bf16x8*)&Asw[buf][(wr * 32 + am * 16 + li) * 72 + kk * 32 + g * 8];
#pragma unroll
      for (int bn = 0; bn < 2; ++bn)
        bfv[bn][kk] = *(const bf16x8*)&Bsw[buf][(wc * 32 + bn * 16 + li) * 72 + kk * 32 + g * 8];
    }
#pragma unroll
    for (int kk = 0; kk < 2; ++kk)
#pragma unroll
      for (int am = 0; am < 2; ++am)
#pragma unroll
        for (int bn = 0; bn < 2; ++bn)
          acc[am][bn] = __builtin_amdgcn_mfma_f32_16x16x32_bf16(
              af[am][kk], bfv[bn][kk], acc[am][bn], 0, 0, 0);
    __syncthreads();
    buf ^= 1;
  }
#pragma unroll
  for (int am = 0; am < 2; ++am)
#pragma unroll
    for (int i = 0; i < 4; ++i) {
      int grow = m0 + wr * 32 + am * 16 + g * 4 + i;
#pragma unroll
      for (int bn = 0; bn < 2; ++bn) {
        int gcol = n0 + wc * 32 + bn * 16 + li;
        mtb[(size_t)grow * DD + gcol] = f2bf(acc[am][bn][i]);
      }
    }
}

// ---- L2 kU: u-dots (0..128) + a-dots from pbf (129..384) + zero/seed (385) --
__global__ __launch_bounds__(256) void kU(
    const float* __restrict__ Wv, const float* __restrict__ bv,
    float* __restrict__ ws, const short* __restrict__ pbf,
    float* __restrict__ out) {
  const int wave = threadIdx.x >> 6, lane = threadIdx.x & 63;
  int blk = blockIdx.x;
  if (blk < 129) {  // u = Wv . wv ; c0 = bv . wv
    int wid = blk * 4 + wave;
    if (wid > 512) return;
    if (wid < 512) {
      float s = wave_dot512(Wv + (size_t)wid * DD, ws + WS_WV, lane);
      if (lane == 0) ws[WS_U + wid] = s;
    } else {
      float s = wave_dot512(bv, ws + WS_WV, lane);
      if (lane == 0) ws[WS_SC + 0] = s;
    }
  } else if (blk < 385) {  // a[row] = pbf[row,:] . wqbk  (4 rows per wave)
    const float* y = ws + WS_WQBK;
    float4 y0 = *(const float4*)&y[lane * 8];
    float4 y1 = *(const float4*)&y[lane * 8 + 4];
    int base = (((blk - 129) * 4 + wave)) * 4;  // 0,4,...,4092
#pragma unroll
    for (int r = 0; r < 4; ++r) {
      int row = base + r;
      bf16x8 v = *(const bf16x8*)&pbf[(size_t)row * DD + lane * 8];
      float4 x0 = make_float4(bf2f(v[0]), bf2f(v[1]), bf2f(v[2]), bf2f(v[3]));
      float4 x1 = make_float4(bf2f(v[4]), bf2f(v[5]), bf2f(v[6]), bf2f(v[7]));
      float s = wave_red(dot8(x0, x1, y0, y1));
      if (lane == 0) ws[WS_A + row] = s;
    }
  } else {  // zero z/w accumulators + tickets, seed value outputs with c1
    float4 zz = make_float4(0.f, 0.f, 0.f, 0.f);
#pragma unroll
    for (int k = 0; k < 8; ++k)
      *(float4*)&ws[WS_Z + (threadIdx.x * 8 + k) * 4] = zz;
    if (threadIdx.x < 64) ((unsigned*)(ws + WS_CNT))[threadIdx.x] = 0u;
    if (threadIdx.x < 8) out[OUT_VALUE + threadIdx.x] = ws[WS_SC + 1];
  }
}

// ---- 64x64-tile 4-wave GEMM, BK=64, gload_lds + XOR granule swizzle --------
// MODE 1: id<512: tbf = pbf . mtb^T (m=id&63, n=id>>6 -> XCD=m%8);
//         id>=512: slot prep (bf16 cvt + e/vv/cs dots).
// MODE 2: scores = tbf . sbf^T + epilogue (512 blocks, b=id&7 -> XCD=b)
//         + per-(b,m) ticket: 8th block finalizes value contribution.
template <int MODE>
__global__ __launch_bounds__(256) void k64(
    const short* __restrict__ A, const short* __restrict__ B,
    short* __restrict__ Cb, const float* __restrict__ slotp,
    const float* __restrict__ Wc, float* __restrict__ ws,
    const float* __restrict__ sbias, const int* __restrict__ maskp,
    const float* __restrict__ bc, float* __restrict__ out,
    short* __restrict__ sbf) {
  __shared__ alignas(16) short SH[4][4096];  // 32KB: [0..1]=A bufs, [2..3]=B bufs
  __shared__ unsigned tick;
  const int wave = threadIdx.x >> 6, lane = threadIdx.x & 63;
  const int id = blockIdx.x;

  if (MODE == 1 && id >= 512) {  // slot prep: bf16 cvt + e/vv/cs row-dots
    int wid = (id - 512) * 4 + wave;  // 0..4095
    const float* row = slotp + (size_t)wid * DD;
    float4 x0 = *(const float4*)&row[lane * 8];
    float4 x1 = *(const float4*)&row[lane * 8 + 4];
    *(bf16x8*)&sbf[(size_t)wid * DD + lane * 8] = cvt8(x0, x1);
    const float* y = ws + WS_WKBQ;
    float4 y0 = *(const float4*)&y[lane * 8];
    float4 y1 = *(const float4*)&y[lane * 8 + 4];
    const float* u = ws + WS_U;
    float4 u0 = *(const float4*)&u[lane * 8];
    float4 u1 = *(const float4*)&u[lane * 8 + 4];
    const float* c = Wc + DD;
    float4 c0 = *(const float4*)&c[lane * 8];
    float4 c1 = *(const float4*)&c[lane * 8 + 4];
    float de = wave_red(dot8(x0, x1, y0, y1));
    float dv = wave_red(dot8(x0, x1, u0, u1));
    float dc = wave_red(dot8(x0, x1, c0, c1));
    if (lane == 0) {
      ws[WS_E + wid] = de;
      ws[WS_VV + wid] = dv + ws[WS_SC + 0];
      ws[WS_CS + wid] = dc;
    }
    return;
  }

  const int wr = wave >> 1, wc = wave & 1;
  const int li = lane & 15, g = lane >> 4;
  int b = 0, m0, n0;
  if (MODE == 1) { m0 = (id & 63) * 64; n0 = (id >> 6) * 64; }
  else           { b = id & 7; m0 = ((id >> 6) & 7) * 64; n0 = ((id >> 3) & 7) * 64; }
  const short* Ab = A + (size_t)b * NP * DD;
  const short* Bb = B + (size_t)b * NS * DD;
  f32x4 acc[2][2] = {};
  float4 sb4r[4];
  int4 mk4r[4];
  const int er = threadIdx.x >> 2, eq = threadIdx.x & 3;
  const size_t ebase = ((size_t)b * NP + m0 + er) * NS + n0 + eq * 16;

  auto stage = [&](int bufi, int k0) {
#pragma unroll
    for (int h = 0; h < 2; ++h) {
      int s = h * 256 + threadIdx.x;
      int row = s >> 3;
      int gsrc = (s & 7) ^ (row & 7);
      async_copy16(Ab + (size_t)(m0 + row) * DD + k0 + gsrc * 8, &SH[bufi][s * 8]);
      async_copy16(Bb + (size_t)(n0 + row) * DD + k0 + gsrc * 8, &SH[2 + bufi][s * 8]);
    }
  };

  stage(0, 0);
  __syncthreads();
  int buf = 0;
  for (int k0 = 0; k0 < DD; k0 += 64) {
    if (k0 + 64 < DD) stage(buf ^ 1, k0 + 64);
    if (MODE == 2) {
      if (k0 == 256) {
#pragma unroll
        for (int h = 0; h < 4; ++h) sb4r[h] = *(const float4*)&sbias[ebase + h * 4];
      } else if (k0 == 384) {
#pragma unroll
        for (int h = 0; h < 4; ++h) mk4r[h] = *(const int4*)&maskp[ebase + h * 4];
      }
    }
    bf16x8 af[2][2], bfv[2][2];
#pragma unroll
    for (int kk = 0; kk < 2; ++kk) {
#pragma unroll
      for (int am = 0; am < 2; ++am) {
        int row = wr * 32 + am * 16 + li;
        af[am][kk] = *(const bf16x8*)&SH[buf][(row * 8 + ((kk * 4 + g) ^ (row & 7))) * 8];
      }
#pragma unroll
      for (int bn = 0; bn < 2; ++bn) {
        int row = wc * 32 + bn * 16 + li;
        bfv[bn][kk] = *(const bf16x8*)&SH[2 + buf][(row * 8 + ((kk * 4 + g) ^ (row & 7))) * 8];
      }
    }
#pragma unroll
    for (int kk = 0; kk < 2; ++kk)
#pragma unroll
      for (int am = 0; am < 2; ++am)
#pragma unroll
        for (int bn = 0; bn < 2; ++bn)
          acc[am][bn] = __builtin_amdgcn_mfma_f32_16x16x32_bf16(
              af[am][kk], bfv[bn][kk], acc[am][bn], 0, 0, 0);
    if (k0 + 64 < DD) {
      __syncthreads();
      buf ^= 1;
    }
  }
  __syncthreads();  // LDS now free for the transposed store

  if (MODE == 1) {
    // stage C tile as bf16 [64][68] in LDS, then 16B-coalesced global writes
    short* cs = &SH[0][0];
#pragma unroll
    for (int am = 0; am < 2; ++am)
#pragma unroll
      for (int i = 0; i < 4; ++i) {
        int row = wr * 32 + am * 16 + g * 4 + i;
#pragma unroll
        for (int bn = 0; bn < 2; ++bn)
          cs[row * 68 + wc * 32 + bn * 16 + li] = f2bf(acc[am][bn][i]);
      }
    __syncthreads();
    int r = threadIdx.x >> 2, q = threadIdx.x & 3;
#pragma unroll
    for (int h = 0; h < 2; ++h) {
      bf16x8 v = *(const bf16x8*)&cs[r * 68 + q * 16 + h * 8];
      *(bf16x8*)&Cb[(size_t)(m0 + r) * DD + n0 + q * 16 + h * 8] = v;
    }
  } else {
    // stage C tile as f32 [64][68] in LDS, then fully vectorized epilogue
    float* cf = (float*)&SH[0][0];
#pragma unroll
    for (int am = 0; am < 2; ++am)
#pragma unroll
      for (int i = 0; i < 4; ++i) {
        int row = wr * 32 + am * 16 + g * 4 + i;
#pragma unroll
        for (int bn = 0; bn < 2; ++bn)
          cf[row * 68 + wc * 32 + bn * 16 + li] = acc[am][bn][i];
      }
    __syncthreads();
    const float sbb = ws[WS_SC + 2];
    const float bcv = *bc;
    int p = m0 + er;
    float av = ws[WS_A + b * NP + p] + sbb;
    float cpv = ws[WS_CP + b * NP + p] + bcv;
    float zp = 0.f, wp = 0.f;
#pragma unroll
    for (int h = 0; h < 4; ++h) {
      int c = eq * 16 + h * 4;
      int scol = n0 + c;
      size_t idx = ebase + h * 4;
      float4 a4 = *(const float4*)&cf[er * 68 + c];
      float4 sb4 = sb4r[h];
      int4 mk4 = mk4r[h];
      float4 e4 = *(const float4*)&ws[WS_E + b * NS + scol];
      float4 vv4 = *(const float4*)&ws[WS_VV + b * NS + scol];
      float4 cs4 = *(const float4*)&ws[WS_CS + b * NS + scol];
      float4 v;
      v.x = (mk4.x == 0) ? NEGBIG : fmaf(a4.x + av + e4.x, INV64, sb4.x);
      v.y = (mk4.y == 0) ? NEGBIG : fmaf(a4.y + av + e4.y, INV64, sb4.y);
      v.z = (mk4.z == 0) ? NEGBIG : fmaf(a4.z + av + e4.z, INV64, sb4.z);
      v.w = (mk4.w == 0) ? NEGBIG : fmaf(a4.w + av + e4.w, INV64, sb4.w);
      *(float4*)&out[OUT_SCORES + idx] = v;
      float e;
      e = exp2f(v.x * LOG2E); zp += e; wp += e * vv4.x;
      e = exp2f(v.y * LOG2E); zp += e; wp += e * vv4.y;
      e = exp2f(v.z * LOG2E); zp += e; wp += e * vv4.z;
      e = exp2f(v.w * LOG2E); zp += e; wp += e * vv4.w;
      float4 cm = make_float4(cpv + cs4.x, cpv + cs4.y, cpv + cs4.z, cpv + cs4.w);
      *(float4*)&out[OUT_COMP + idx] = cm;
    }
    zp += __shfl_xor(zp, 1); zp += __shfl_xor(zp, 2);
    wp += __shfl_xor(wp, 1); wp += __shfl_xor(wp, 2);
    if (eq == 0) {
      atomicAdd(&ws[WS_Z + b * NP + p], zp);
      atomicAdd(&ws[WS_W + b * NP + p], wp);
    }
    // ---- per-(b,m) ticket; 8th block finalizes the value contribution ----
    __syncthreads();
    if (threadIdx.x == 0)
      tick = atomicAdd((unsigned*)(ws + WS_CNT) + (b * 8 + ((id >> 6) & 7)), 1u);
    __syncthreads();
    if (tick == 7 && threadIdx.x < 64) {
      int pr = m0 + threadIdx.x;
      float zz = atomicAdd(&ws[WS_Z + b * NP + pr], 0.0f);
      float ww = atomicAdd(&ws[WS_W + b * NP + pr], 0.0f);
      float v = wave_red(ww / zz);
      if (threadIdx.x == 0) atomicAdd(&out[OUT_VALUE + b], v * (1.0f / NP));
    }
  }
}

extern "C" void kernel_launch(void* const* d_in, const int* in_sizes, int n_in,
                              void* d_out, int out_size, void* d_ws,
                              size_t ws_size, hipStream_t stream) {
  const float* piece = (const float*)d_in[0];
  const float* slot = (const float*)d_in[1];
  const int* mask = (const int*)d_in[2];
  const float* sbias = (const float*)d_in[3];
  const float* Wq = (const float*)d_in[4];
  const float* bq = (const float*)d_in[5];
  const float* Wk = (const float*)d_in[6];
  const float* bk = (const float*)d_in[7];
  const float* Wv = (const float*)d_in[8];
  const float* bv = (const float*)d_in[9];
  const float* Wo = (const float*)d_in[10];
  const float* bo = (const float*)d_in[11];
  const float* Wc = (const float*)d_in[12];
  const float* bc = (const float*)d_in[13];
  const float* Wval = (const float*)d_in[14];
  const float* bval = (const float*)d_in[15];
  float* out = (float*)d_out;
  float* ws = (float*)d_ws;

  short* mtb = (short*)(ws + WS_MTBF);
  short* tbf = (short*)(ws + WS_TBF);
  short* pbf = (short*)(ws + WS_PBF);
  short* sbf = (short*)(ws + WS_SBF);

  // L1: row-dots + MT GEMM + piece cvt/cp-dot (all input-only dependencies)
  hipLaunchKernelGGL(kAM, dim3(1473), dim3(256), 0, stream,
                     Wo, Wval, Wq, bk, Wk, bq, bo, bval, piece, Wc, ws, mtb, pbf);
  // L2: u-dots + a-dots (from pbf) + zero/seed  (small)
  hipLaunchKernelGGL(kU, dim3(386), dim3(256), 0, stream, Wv, bv, ws, pbf, out);
  // L3: tbf = pbf . mtb^T (512 GEMM blocks) + slot prep (1024 blocks)
  hipLaunchKernelGGL((k64<1>), dim3(1536), dim3(256), 0, stream,
                     pbf, mtb, tbf, slot, Wc, ws,
                     (const float*)nullptr, (const int*)nullptr,
                     (const float*)nullptr, (float*)nullptr, sbf);
  // L4: scores/comp/softmax partials + fused value finalization
  hipLaunchKernelGGL((k64<2>), dim3(512), dim3(256), 0, stream,
                     tbf, sbf, (short*)nullptr, (const float*)nullptr,
                     (const float*)nullptr, ws, sbias, mask, bc, out,
                     (short*)nullptr);
}

// Round 18
// 42.933 us; speedup vs baseline: 1.0316x; 1.0316x over previous
//
#include <hip/hip_runtime.h>
#include <math.h>

#define NP 512
#define NS 512
#define DD 512
#define INV64 0.015625f
#define NEGBIG -1000000000.0f
#define LOG2E 1.4426950408889634f

// ws float offsets
#define WS_MTBF   0         // 512*512 bf16
#define WS_TBF    131072    // 4096*512 bf16
#define WS_PBF    1179648   // 4096*512 bf16
#define WS_SBF    2228224   // 4096*512 bf16
#define WS_WV     3538944   // 512
#define WS_U      3539456   // 512
#define WS_WQBK   3539968   // 512
#define WS_WKBQ   3540480   // 512
#define WS_VV     3540992   // 4096
#define WS_A      3545088   // 4096
#define WS_E      3549184   // 4096
#define WS_CP     3553280   // 4096
#define WS_CS     3557376   // 4096
#define WS_Z      3561472   // 4096
#define WS_W      3565568   // 4096 (must be WS_Z+4096: zeroed together)
#define WS_SC     3569664   // [0]=bv.wv [1]=bo.Wval+bval [2]=bq.bk
#define WS_CNT    3569680   // 64 unsigned ticket counters (zeroed by kCp)

#define OUT_SCORES 0
#define OUT_VALUE  2097152
#define OUT_COMP   2097160

typedef short bf16x8 __attribute__((ext_vector_type(8)));
typedef float f32x4 __attribute__((ext_vector_type(4)));

__device__ __forceinline__ short f2bf(float f) {
  unsigned u = __builtin_bit_cast(unsigned, f);
  u += 0x7fffu + ((u >> 16) & 1u);
  return (short)(u >> 16);
}

__device__ __forceinline__ bf16x8 cvt8(float4 a, float4 b) {
  bf16x8 o;
  o[0] = f2bf(a.x); o[1] = f2bf(a.y); o[2] = f2bf(a.z); o[3] = f2bf(a.w);
  o[4] = f2bf(b.x); o[5] = f2bf(b.y); o[6] = f2bf(b.z); o[7] = f2bf(b.w);
  return o;
}

__device__ __forceinline__ void async_copy16(const void* g, void* l) {
  __builtin_amdgcn_global_load_lds(
      (const __attribute__((address_space(1))) unsigned int*)g,
      (__attribute__((address_space(3))) unsigned int*)l, 16, 0, 0);
}

__device__ __forceinline__ float dot8(float4 a0, float4 a1, float4 b0, float4 b1) {
  return a0.x * b0.x + a0.y * b0.y + a0.z * b0.z + a0.w * b0.w +
         a1.x * b1.x + a1.y * b1.y + a1.z * b1.z + a1.w * b1.w;
}

__device__ __forceinline__ float wave_red(float s) {
#pragma unroll
  for (int o = 32; o; o >>= 1) s += __shfl_xor(s, o);
  return s;
}

__device__ inline float wave_dot512(const float* __restrict__ x,
                                    const float* __restrict__ y, int lane) {
  float4 x0 = *(const float4*)&x[lane * 8];
  float4 x1 = *(const float4*)&x[lane * 8 + 4];
  float4 y0 = *(const float4*)&y[lane * 8];
  float4 y1 = *(const float4*)&y[lane * 8 + 4];
  return wave_red(dot8(x0, x1, y0, y1));
}

// ---- L1 kAM: row-dots (blocks 0..384) + MT = Wk.Wq^T from f32 (385..448) ----
__global__ __launch_bounds__(256) void kAM(
    const float* __restrict__ Wo, const float* __restrict__ Wval,
    const float* __restrict__ Wq, const float* __restrict__ bk,
    const float* __restrict__ Wk, const float* __restrict__ bq,
    const float* __restrict__ bo, const float* __restrict__ bval,
    float* __restrict__ ws, short* __restrict__ mtb) {
  __shared__ alignas(16) short Asw[2][64 * 72];
  __shared__ alignas(16) short Bsw[2][64 * 72];
  int blk = blockIdx.x;
  if (blk < 385) {
    int wid = blk * 4 + (threadIdx.x >> 6);
    int lane = threadIdx.x & 63;
    if (wid >= 1538) return;
    const float *x, *y;
    float* dst;
    float extra = 0.f;
    int r = wid & 511;
    if (wid < 512)        { x = Wo + (size_t)r * DD; y = Wval; dst = ws + WS_WV + r; }
    else if (wid < 1024)  { x = Wq + (size_t)r * DD; y = bk;   dst = ws + WS_WQBK + r; }
    else if (wid < 1536)  { x = Wk + (size_t)r * DD; y = bq;   dst = ws + WS_WKBQ + r; }
    else if (wid == 1536) { x = bo; y = Wval; dst = ws + WS_SC + 1; extra = *bval; }
    else                  { x = bq; y = bk;   dst = ws + WS_SC + 2; }
    float s = wave_dot512(x, y, lane);
    if (lane == 0) *dst = s + extra;
    return;
  }
  // MT GEMM: 64 blocks, 64x64 tile, f32 inputs with on-the-fly bf16 cvt
  int gb = blk - 385;
  const int m0 = (gb & 7) * 64, n0 = (gb >> 3) * 64;
  const int wave = threadIdx.x >> 6, lane = threadIdx.x & 63;
  const int wr = wave >> 1, wc = wave & 1;
  const int li = lane & 15, g = lane >> 4;
  const int arow = threadIdx.x >> 2, aseg = threadIdx.x & 3;
  f32x4 acc[2][2] = {};

  auto stage = [&](int bufi, int k0) {
    const float* sa = Wk + (size_t)(m0 + arow) * DD + k0 + aseg * 16;
    float4 a0 = *(const float4*)sa, a1 = *(const float4*)(sa + 4);
    float4 a2 = *(const float4*)(sa + 8), a3 = *(const float4*)(sa + 12);
    const float* sb = Wq + (size_t)(n0 + arow) * DD + k0 + aseg * 16;
    float4 b0 = *(const float4*)sb, b1 = *(const float4*)(sb + 4);
    float4 b2 = *(const float4*)(sb + 8), b3 = *(const float4*)(sb + 12);
    *(bf16x8*)&Asw[bufi][arow * 72 + aseg * 16] = cvt8(a0, a1);
    *(bf16x8*)&Asw[bufi][arow * 72 + aseg * 16 + 8] = cvt8(a2, a3);
    *(bf16x8*)&Bsw[bufi][arow * 72 + aseg * 16] = cvt8(b0, b1);
    *(bf16x8*)&Bsw[bufi][arow * 72 + aseg * 16 + 8] = cvt8(b2, b3);
  };

  stage(0, 0);
  __syncthreads();
  int buf = 0;
  for (int k0 = 0; k0 < DD; k0 += 64) {
    if (k0 + 64 < DD) stage(buf ^ 1, k0 + 64);
    bf16x8 af[2][2], bfv[2][2];
#pragma unroll
    for (int kk = 0; kk < 2; ++kk) {
#pragma unroll
      for (int am = 0; am < 2; ++am)
        af[am][kk] = *(const bf16x8*)&Asw[buf][(wr * 32 + am * 16 + li) * 72 + kk * 32 + g * 8];
#pragma unroll
      for (int bn = 0; bn < 2; ++bn)
        bfv[bn][kk] = *(const bf16x8*)&Bsw[buf][(wc * 32 + bn * 16 + li) * 72 + kk * 32 + g * 8];
    }
#pragma unroll
    for (int kk = 0; kk < 2; ++kk)
#pragma unroll
      for (int am = 0; am < 2; ++am)
#pragma unroll
        for (int bn = 0; bn < 2; ++bn)
          acc[am][bn] = __builtin_amdgcn_mfma_f32_16x16x32_bf16(
              af[am][kk], bfv[bn][kk], acc[am][bn], 0, 0, 0);
    __syncthreads();
    buf ^= 1;
  }
#pragma unroll
  for (int am = 0; am < 2; ++am)
#pragma unroll
    for (int i = 0; i < 4; ++i) {
      int grow = m0 + wr * 32 + am * 16 + g * 4 + i;
#pragma unroll
      for (int bn = 0; bn < 2; ++bn) {
        int gcol = n0 + wc * 32 + bn * 16 + li;
        mtb[(size_t)grow * DD + gcol] = f2bf(acc[am][bn][i]);
      }
    }
}

// ---- L2 kCp: piece prep (0..1023) + u-dots (1024..1152) + zero/seed (1153) --
__global__ __launch_bounds__(256) void kCp(
    const float* __restrict__ piece, const float* __restrict__ Wv,
    const float* __restrict__ bv, const float* __restrict__ Wc,
    float* __restrict__ ws, short* __restrict__ pbf, float* __restrict__ out) {
  int lane = threadIdx.x & 63;
  if (blockIdx.x < 1024) {
    int wid = blockIdx.x * 4 + (threadIdx.x >> 6);  // 0..4095
    const float* row = piece + (size_t)wid * DD;
    float4 x0 = *(const float4*)&row[lane * 8];
    float4 x1 = *(const float4*)&row[lane * 8 + 4];
    bf16x8 o;
    o[0] = f2bf(x0.x); o[1] = f2bf(x0.y); o[2] = f2bf(x0.z); o[3] = f2bf(x0.w);
    o[4] = f2bf(x1.x); o[5] = f2bf(x1.y); o[6] = f2bf(x1.z); o[7] = f2bf(x1.w);
    *(bf16x8*)&pbf[(size_t)wid * DD + lane * 8] = o;
    const float* y = ws + WS_WQBK;
    float4 y0 = *(const float4*)&y[lane * 8];
    float4 y1 = *(const float4*)&y[lane * 8 + 4];
    float4 c0 = *(const float4*)&Wc[lane * 8];
    float4 c1 = *(const float4*)&Wc[lane * 8 + 4];
    float da = wave_red(dot8(x0, x1, y0, y1));
    float dc = wave_red(dot8(x0, x1, c0, c1));
    if (lane == 0) { ws[WS_A + wid] = da; ws[WS_CP + wid] = dc; }
  } else if (blockIdx.x < 1153) {
    int wid = ((int)blockIdx.x - 1024) * 4 + (threadIdx.x >> 6);
    if (wid > 512) return;
    if (wid < 512) {
      float s = wave_dot512(Wv + (size_t)wid * DD, ws + WS_WV, lane);
      if (lane == 0) ws[WS_U + wid] = s;
    } else {
      float s = wave_dot512(bv, ws + WS_WV, lane);
      if (lane == 0) ws[WS_SC + 0] = s;
    }
  } else {
    // zero z/w accumulators + tickets, seed value outputs with c1
    float4 zz = make_float4(0.f, 0.f, 0.f, 0.f);
#pragma unroll
    for (int k = 0; k < 8; ++k)
      *(float4*)&ws[WS_Z + (threadIdx.x * 8 + k) * 4] = zz;
    if (threadIdx.x < 64) ((unsigned*)(ws + WS_CNT))[threadIdx.x] = 0u;
    if (threadIdx.x < 8) out[OUT_VALUE + threadIdx.x] = ws[WS_SC + 1];
  }
}

// ---- 64x64-tile 4-wave GEMM, BK=64, gload_lds + XOR granule swizzle --------
// MODE 1: id<512: tbf = pbf . mtb^T (m=id&63, n=id>>6 -> XCD=m%8);
//         id>=512: slot prep (bf16 cvt + e/vv/cs dots).
// MODE 2: scores = tbf . sbf^T + epilogue (512 blocks, b=id&7 -> XCD=b)
//         + per-(b,m) ticket: 8th block finalizes value contribution.
template <int MODE>
__global__ __launch_bounds__(256) void k64(
    const short* __restrict__ A, const short* __restrict__ B,
    short* __restrict__ Cb, const float* __restrict__ slotp,
    const float* __restrict__ Wc, float* __restrict__ ws,
    const float* __restrict__ sbias, const int* __restrict__ maskp,
    const float* __restrict__ bc, float* __restrict__ out,
    short* __restrict__ sbf) {
  __shared__ alignas(16) short SH[4][4096];  // 32KB: [0..1]=A bufs, [2..3]=B bufs
  __shared__ unsigned tick;
  const int wave = threadIdx.x >> 6, lane = threadIdx.x & 63;
  const int id = blockIdx.x;

  if (MODE == 1 && id >= 512) {  // slot prep: bf16 cvt + e/vv/cs row-dots
    int wid = (id - 512) * 4 + wave;  // 0..4095
    const float* row = slotp + (size_t)wid * DD;
    float4 x0 = *(const float4*)&row[lane * 8];
    float4 x1 = *(const float4*)&row[lane * 8 + 4];
    bf16x8 o;
    o[0] = f2bf(x0.x); o[1] = f2bf(x0.y); o[2] = f2bf(x0.z); o[3] = f2bf(x0.w);
    o[4] = f2bf(x1.x); o[5] = f2bf(x1.y); o[6] = f2bf(x1.z); o[7] = f2bf(x1.w);
    *(bf16x8*)&sbf[(size_t)wid * DD + lane * 8] = o;
    const float* y = ws + WS_WKBQ;
    float4 y0 = *(const float4*)&y[lane * 8];
    float4 y1 = *(const float4*)&y[lane * 8 + 4];
    const float* u = ws + WS_U;
    float4 u0 = *(const float4*)&u[lane * 8];
    float4 u1 = *(const float4*)&u[lane * 8 + 4];
    const float* c = Wc + DD;
    float4 c0 = *(const float4*)&c[lane * 8];
    float4 c1 = *(const float4*)&c[lane * 8 + 4];
    float de = wave_red(dot8(x0, x1, y0, y1));
    float dv = wave_red(dot8(x0, x1, u0, u1));
    float dc = wave_red(dot8(x0, x1, c0, c1));
    if (lane == 0) {
      ws[WS_E + wid] = de;
      ws[WS_VV + wid] = dv + ws[WS_SC + 0];
      ws[WS_CS + wid] = dc;
    }
    return;
  }

  const int wr = wave >> 1, wc = wave & 1;
  const int li = lane & 15, g = lane >> 4;
  int b = 0, m0, n0;
  if (MODE == 1) { m0 = (id & 63) * 64; n0 = (id >> 6) * 64; }
  else           { b = id & 7; m0 = ((id >> 6) & 7) * 64; n0 = ((id >> 3) & 7) * 64; }
  const short* Ab = A + (size_t)b * NP * DD;
  const short* Bb = B + (size_t)b * NS * DD;
  f32x4 acc[2][2] = {};
  float4 sb4r[4];
  int4 mk4r[4];
  const int er = threadIdx.x >> 2, eq = threadIdx.x & 3;
  const size_t ebase = ((size_t)b * NP + m0 + er) * NS + n0 + eq * 16;

  auto stage = [&](int bufi, int k0) {
#pragma unroll
    for (int h = 0; h < 2; ++h) {
      int s = h * 256 + threadIdx.x;
      int row = s >> 3;
      int gsrc = (s & 7) ^ (row & 7);
      async_copy16(Ab + (size_t)(m0 + row) * DD + k0 + gsrc * 8, &SH[bufi][s * 8]);
      async_copy16(Bb + (size_t)(n0 + row) * DD + k0 + gsrc * 8, &SH[2 + bufi][s * 8]);
    }
  };

  stage(0, 0);
  __syncthreads();
  int buf = 0;
  for (int k0 = 0; k0 < DD; k0 += 64) {
    if (k0 + 64 < DD) stage(buf ^ 1, k0 + 64);
    if (MODE == 2) {
      if (k0 == 256) {
#pragma unroll
        for (int h = 0; h < 4; ++h)
          sb4r[h] = *(const float4*)&sbias[ebase + h * 4];
      } else if (k0 == 384) {
#pragma unroll
        for (int h = 0; h < 4; ++h)
          mk4r[h] = *(const int4*)&maskp[ebase + h * 4];
      }
    }
    bf16x8 af[2][2], bfv[2][2];
#pragma unroll
    for (int kk = 0; kk < 2; ++kk) {
#pragma unroll
      for (int am = 0; am < 2; ++am) {
        int row = wr * 32 + am * 16 + li;
        af[am][kk] = *(const bf16x8*)&SH[buf][(row * 8 + ((kk * 4 + g) ^ (row & 7))) * 8];
      }
#pragma unroll
      for (int bn = 0; bn < 2; ++bn) {
        int row = wc * 32 + bn * 16 + li;
        bfv[bn][kk] = *(const bf16x8*)&SH[2 + buf][(row * 8 + ((kk * 4 + g) ^ (row & 7))) * 8];
      }
    }
#pragma unroll
    for (int kk = 0; kk < 2; ++kk)
#pragma unroll
      for (int am = 0; am < 2; ++am)
#pragma unroll
        for (int bn = 0; bn < 2; ++bn)
          acc[am][bn] = __builtin_amdgcn_mfma_f32_16x16x32_bf16(
              af[am][kk], bfv[bn][kk], acc[am][bn], 0, 0, 0);
    if (k0 + 64 < DD) {
      __syncthreads();
      buf ^= 1;
    }
  }
  __syncthreads();  // LDS now free for the transposed store

  if (MODE == 1) {
    // stage C tile as bf16 [64][68] in LDS, then 16B-coalesced global writes
    short* cs = &SH[0][0];
#pragma unroll
    for (int am = 0; am < 2; ++am)
#pragma unroll
      for (int i = 0; i < 4; ++i) {
        int row = wr * 32 + am * 16 + g * 4 + i;
#pragma unroll
        for (int bn = 0; bn < 2; ++bn)
          cs[row * 68 + wc * 32 + bn * 16 + li] = f2bf(acc[am][bn][i]);
      }
    __syncthreads();
    int r = threadIdx.x >> 2, q = threadIdx.x & 3;
#pragma unroll
    for (int h = 0; h < 2; ++h) {
      bf16x8 v = *(const bf16x8*)&cs[r * 68 + q * 16 + h * 8];
      *(bf16x8*)&Cb[(size_t)(m0 + r) * DD + n0 + q * 16 + h * 8] = v;
    }
  } else {
    // stage C tile as f32 [64][68] in LDS, then fully vectorized epilogue
    float* cf = (float*)&SH[0][0];
#pragma unroll
    for (int am = 0; am < 2; ++am)
#pragma unroll
      for (int i = 0; i < 4; ++i) {
        int row = wr * 32 + am * 16 + g * 4 + i;
#pragma unroll
        for (int bn = 0; bn < 2; ++bn)
          cf[row * 68 + wc * 32 + bn * 16 + li] = acc[am][bn][i];
      }
    __syncthreads();
    const float sbb = ws[WS_SC + 2];
    const float bcv = *bc;
    int p = m0 + er;
    float av = ws[WS_A + b * NP + p] + sbb;
    float cpv = ws[WS_CP + b * NP + p] + bcv;
    float zp = 0.f, wp = 0.f;
#pragma unroll
    for (int h = 0; h < 4; ++h) {
      int c = eq * 16 + h * 4;
      int scol = n0 + c;
      size_t idx = ebase + h * 4;
      float4 a4 = *(const float4*)&cf[er * 68 + c];
      float4 sb4 = sb4r[h];
      int4 mk4 = mk4r[h];
      float4 e4 = *(const float4*)&ws[WS_E + b * NS + scol];
      float4 vv4 = *(const float4*)&ws[WS_VV + b * NS + scol];
      float4 cs4 = *(const float4*)&ws[WS_CS + b * NS + scol];
      float4 v;
      v.x = (mk4.x == 0) ? NEGBIG : fmaf(a4.x + av + e4.x, INV64, sb4.x);
      v.y = (mk4.y == 0) ? NEGBIG : fmaf(a4.y + av + e4.y, INV64, sb4.y);
      v.z = (mk4.z == 0) ? NEGBIG : fmaf(a4.z + av + e4.z, INV64, sb4.z);
      v.w = (mk4.w == 0) ? NEGBIG : fmaf(a4.w + av + e4.w, INV64, sb4.w);
      *(float4*)&out[OUT_SCORES + idx] = v;
      float e;
      e = exp2f(v.x * LOG2E); zp += e; wp += e * vv4.x;
      e = exp2f(v.y * LOG2E); zp += e; wp += e * vv4.y;
      e = exp2f(v.z * LOG2E); zp += e; wp += e * vv4.z;
      e = exp2f(v.w * LOG2E); zp += e; wp += e * vv4.w;
      float4 cm = make_float4(cpv + cs4.x, cpv + cs4.y, cpv + cs4.z, cpv + cs4.w);
      *(float4*)&out[OUT_COMP + idx] = cm;
    }
    zp += __shfl_xor(zp, 1); zp += __shfl_xor(zp, 2);
    wp += __shfl_xor(wp, 1); wp += __shfl_xor(wp, 2);
    if (eq == 0) {
      atomicAdd(&ws[WS_Z + b * NP + p], zp);
      atomicAdd(&ws[WS_W + b * NP + p], wp);
    }
    // ---- per-(b,m) ticket; 8th block finalizes the value contribution ----
    __syncthreads();
    if (threadIdx.x == 0)
      tick = atomicAdd((unsigned*)(ws + WS_CNT) + (b * 8 + ((id >> 6) & 7)), 1u);
    __syncthreads();
    if (tick == 7 && threadIdx.x < 64) {
      int pr = m0 + threadIdx.x;
      float zz = atomicAdd(&ws[WS_Z + b * NP + pr], 0.0f);
      float ww = atomicAdd(&ws[WS_W + b * NP + pr], 0.0f);
      float v = wave_red(ww / zz);
      if (threadIdx.x == 0) atomicAdd(&out[OUT_VALUE + b], v * (1.0f / NP));
    }
  }
}

extern "C" void kernel_launch(void* const* d_in, const int* in_sizes, int n_in,
                              void* d_out, int out_size, void* d_ws,
                              size_t ws_size, hipStream_t stream) {
  const float* piece = (const float*)d_in[0];
  const float* slot = (const float*)d_in[1];
  const int* mask = (const int*)d_in[2];
  const float* sbias = (const float*)d_in[3];
  const float* Wq = (const float*)d_in[4];
  const float* bq = (const float*)d_in[5];
  const float* Wk = (const float*)d_in[6];
  const float* bk = (const float*)d_in[7];
  const float* Wv = (const float*)d_in[8];
  const float* bv = (const float*)d_in[9];
  const float* Wo = (const float*)d_in[10];
  const float* bo = (const float*)d_in[11];
  const float* Wc = (const float*)d_in[12];
  const float* bc = (const float*)d_in[13];
  const float* Wval = (const float*)d_in[14];
  const float* bval = (const float*)d_in[15];
  float* out = (float*)d_out;
  float* ws = (float*)d_ws;

  short* mtb = (short*)(ws + WS_MTBF);
  short* tbf = (short*)(ws + WS_TBF);
  short* pbf = (short*)(ws + WS_PBF);
  short* sbf = (short*)(ws + WS_SBF);

  // L1: row-dots + MT GEMM (f32 inputs, otf cvt)
  hipLaunchKernelGGL(kAM, dim3(449), dim3(256), 0, stream,
                     Wo, Wval, Wq, bk, Wk, bq, bo, bval, ws, mtb);
  // L2: piece prep + u-dots + zero/seed
  hipLaunchKernelGGL(kCp, dim3(1154), dim3(256), 0, stream,
                     piece, Wv, bv, Wc, ws, pbf, out);
  // L3: tbf = pbf . mtb^T (512 GEMM blocks) + slot prep (1024 blocks)
  hipLaunchKernelGGL((k64<1>), dim3(1536), dim3(256), 0, stream,
                     pbf, mtb, tbf, slot, Wc, ws,
                     (const float*)nullptr, (const int*)nullptr,
                     (const float*)nullptr, (float*)nullptr, sbf);
  // L4: scores/comp/softmax partials + fused value finalization
  hipLaunchKernelGGL((k64<2>), dim3(512), dim3(256), 0, stream,
                     tbf, sbf, (short*)nullptr, (const float*)nullptr,
                     (const float*)nullptr, ws, sbias, mask, bc, out,
                     (short*)nullptr);
}